// Round 7
// baseline (59.118 us; speedup 1.0000x reference)
//
#include <hip/hip_runtime.h>
#include <hip/hip_fp16.h>

#define SDIM 1024

typedef _Float16 f16;
typedef _Float16 f16x8 __attribute__((ext_vector_type(8)));
typedef __attribute__((ext_vector_type(4))) float f32x4;

union FragH { unsigned int u[4]; f16x8 f; };
union H2U  { unsigned int u; __half2 h; };

// packed-f16 tanh-gelu on 2 elements (see R5 notes): 10 VALU + 4 trans, no OCML.
__device__ __forceinline__ unsigned int addgelu_pair(unsigned int au, unsigned int bu) {
    const __half2 k044 = __float2half2_rn(0.044715f);
    const __half2 one  = __float2half2_rn(1.0f);
    const __half2 cz   = __float2half2_rn(-2.3022082f);
    H2U A, B, Z, R, G;
    A.u = au; B.u = bu;
    __half2 t  = __hadd2(A.h, B.h);
    __half2 t2 = __hmul2(t, t);
    __half2 pl = __hfma2(t2, k044, one);
    Z.h = __hmul2(__hmul2(t, cz), pl);
    unsigned int zh = Z.u >> 16;
    unsigned int el, eh, dl, dh, rl, rh, ru;
    asm("v_exp_f16 %0, %1"      : "=v"(el) : "v"(Z.u));
    asm("v_exp_f16 %0, %1"      : "=v"(eh) : "v"(zh));
    asm("v_add_f16 %0, %1, 1.0" : "=v"(dl) : "v"(el));
    asm("v_add_f16 %0, %1, 1.0" : "=v"(dh) : "v"(eh));
    asm("v_rcp_f16 %0, %1"      : "=v"(rl) : "v"(dl));
    asm("v_rcp_f16 %0, %1"      : "=v"(rh) : "v"(dh));
    asm("v_pack_b32_f16 %0, %1, %2" : "=v"(ru) : "v"(rl), "v"(rh));
    R.u = ru;
    G.h = __hmul2(t, R.h);
    return G.u;
}

// ---------------- Kernel 1: u[b,s,64] = xc@W1[:32] + b1 ; v = xc@W1[32:] (f16 out) -----
__global__ __launch_bounds__(256) void compute_uv(
    const float* __restrict__ x, const float* __restrict__ Wc,
    const float* __restrict__ bc, const float* __restrict__ W1,
    const float* __restrict__ b1, f16* __restrict__ u, f16* __restrict__ v)
{
    __shared__ float xrow[4 * 1024];
    __shared__ float part[4 * 8 * 32];
    __shared__ float xc[4 * 32];
    const int tid = threadIdx.x;
    const size_t bs0 = (size_t)blockIdx.x * 4;

    const float4* xin = (const float4*)(x + bs0 * 1024);
    #pragma unroll
    for (int it = 0; it < 4; ++it)
        ((float4*)xrow)[it * 256 + tid] = xin[it * 256 + tid];
    __syncthreads();

    {
        const int c = tid & 31, p = tid >> 5;
        float acc[4] = {0.f, 0.f, 0.f, 0.f};
        #pragma unroll 4
        for (int dd = 0; dd < 128; ++dd) {
            const int d = p * 128 + dd;
            const float wv = Wc[d * 32 + c];
            #pragma unroll
            for (int r = 0; r < 4; ++r)
                acc[r] = __builtin_fmaf(xrow[r * 1024 + d], wv, acc[r]);
        }
        #pragma unroll
        for (int r = 0; r < 4; ++r)
            part[r * 256 + p * 32 + c] = acc[r];
    }
    __syncthreads();
    if (tid < 128) {
        const int r = tid >> 5, c = tid & 31;
        float s = bc[c];
        #pragma unroll
        for (int p = 0; p < 8; ++p) s += part[r * 256 + p * 32 + c];
        xc[r * 32 + c] = s;
    }
    __syncthreads();
    {
        const int h = tid & 63;
        const int rr = tid >> 6;
        float ua = b1[h], va = 0.0f;
        #pragma unroll
        for (int cc = 0; cc < 32; ++cc) {
            const float xv = xc[rr * 32 + cc];
            ua = __builtin_fmaf(xv, W1[cc * 64 + h], ua);
            va = __builtin_fmaf(xv, W1[(32 + cc) * 64 + h], va);
        }
        u[(bs0 + rr) * 64 + h] = (f16)ua;
        v[(bs0 + rr) * 64 + h] = (f16)va;
    }
}

// ---------------- Kernel 2: out[b,h,i,j] = sum_k gelu(u[i,k]+v[j,k]) * W2[k,h] + b2[h] --
// Same MFMA math as R5 (D rows = j-in-tile, cols = h). LDS-transpose epilogue:
// acc for 4 i-rows staged in o_lds (XOR-swizzled slot^h), stored with lanes remapped
// so each 16-lane group writes 256 B contiguous per (h,i) row. Grid (16,32,2).
__global__ __launch_bounds__(256, 4) void prg_main(
    const f16* __restrict__ u, const f16* __restrict__ v,
    const float* __restrict__ W2, const float* __restrict__ b2,
    float* __restrict__ out)
{
    const int tid  = threadIdx.x;
    const int lane = tid & 63;
    const int w    = tid >> 6;
    const int jb   = blockIdx.x * 64;
    const int ib   = blockIdx.y * 32;
    const int b    = blockIdx.z;

    __shared__ f16   u_lds[32][64];      // 4 KB
    __shared__ float o_lds[4][16][64];   // 16 KB, slot-swizzled

    {
        const int row = tid >> 3;
        const int col = (tid & 7) * 8;
        *(uint4*)&u_lds[row][col] =
            *(const uint4*)(u + ((size_t)(b * SDIM + ib + row) * 64 + col));
    }

    const int lg = lane >> 4;   // k-group 0..3
    const int lr = lane & 15;   // A row (j) / B+D col (h)
    const int k0 = lg * 8;

    const int jA = jb + w * 16 + lr;
    const f16* vp = v + ((size_t)(b * SDIM + jA) * 64);
    const uint4 vlo = *(const uint4*)(vp + k0);
    const uint4 vhi = *(const uint4*)(vp + k0 + 32);

    FragH w2lo, w2hi;
    #pragma unroll
    for (int e = 0; e < 4; ++e) {
        H2U a, c;
        a.h = __floats2half2_rn(W2[(k0 + 2*e) * 16 + lr],      W2[(k0 + 2*e + 1) * 16 + lr]);
        c.h = __floats2half2_rn(W2[(k0 + 32 + 2*e) * 16 + lr], W2[(k0 + 32 + 2*e + 1) * 16 + lr]);
        w2lo.u[e] = a.u;
        w2hi.u[e] = c.u;
    }

    const float b2h = b2[lr];

    // epilogue mapping: wave w stores i-row g*4+w; jg = lane&15 (16B j-chunk),
    // hq = (lane>>4)&3, h = hq*4 + it. 16 consecutive lanes -> 256 B contiguous.
    const int jg = lane & 15;
    const int hq = (lane >> 4) & 3;
    // base: out[b, h=hq*4, i=ib+w, jb+jg*4]; it advances ONE h-plane at a time.
    float* pg = out + (((size_t)(b * 16 + hq * 4) * SDIM) + (ib + w)) * SDIM + jb + jg * 4;
    const int wslot = ((w << 2) | lg) ^ lr;   // swizzled write slot

    __syncthreads();

    for (int g = 0; g < 8; ++g) {
        f32x4 acc[4];
        #pragma unroll
        for (int q = 0; q < 4; ++q) {
            const int il = g * 4 + q;
            const uint4 alo = *(const uint4*)&u_lds[il][k0];
            const uint4 ahi = *(const uint4*)&u_lds[il][k0 + 32];

            FragH glo, ghi;
            glo.u[0] = addgelu_pair(alo.x, vlo.x);
            glo.u[1] = addgelu_pair(alo.y, vlo.y);
            glo.u[2] = addgelu_pair(alo.z, vlo.z);
            glo.u[3] = addgelu_pair(alo.w, vlo.w);
            ghi.u[0] = addgelu_pair(ahi.x, vhi.x);
            ghi.u[1] = addgelu_pair(ahi.y, vhi.y);
            ghi.u[2] = addgelu_pair(ahi.z, vhi.z);
            ghi.u[3] = addgelu_pair(ahi.w, vhi.w);

            f32x4 a = {b2h, b2h, b2h, b2h};
            a = __builtin_amdgcn_mfma_f32_16x16x32_f16(glo.f, w2lo.f, a, 0, 0, 0);
            a = __builtin_amdgcn_mfma_f32_16x16x32_f16(ghi.f, w2hi.f, a, 0, 0, 0);
            acc[q] = a;
        }

        __syncthreads();   // previous group's o_lds reads complete
        #pragma unroll
        for (int q = 0; q < 4; ++q)
            *(float4*)&o_lds[q][lr][wslot << 2] = *(float4*)&acc[q];
        __syncthreads();   // o_lds tile ready

        #pragma unroll
        for (int it = 0; it < 4; ++it) {
            const int h = hq * 4 + it;
            const int rslot = jg ^ h;
            const float4 val = *(const float4*)&o_lds[w][h][rslot << 2];
            *(float4*)(pg + (size_t)it * SDIM * SDIM) = val;   // FIX: one h-plane per it
        }
        pg += 4 * SDIM;   // next 4 i-rows
    }
}

extern "C" void kernel_launch(void* const* d_in, const int* in_sizes, int n_in,
                              void* d_out, int out_size, void* d_ws, size_t ws_size,
                              hipStream_t stream) {
    const float* x  = (const float*)d_in[0];
    const float* Wc = (const float*)d_in[1];
    const float* bc = (const float*)d_in[2];
    const float* W1 = (const float*)d_in[3];
    const float* b1 = (const float*)d_in[4];
    const float* W2 = (const float*)d_in[5];
    const float* b2 = (const float*)d_in[6];
    float* out = (float*)d_out;

    f16* u = (f16*)d_ws;
    f16* v = u + 2 * SDIM * 64;

    compute_uv<<<dim3(512), dim3(256), 0, stream>>>(x, Wc, bc, W1, b1, u, v);
    prg_main<<<dim3(16, 32, 2), dim3(256), 0, stream>>>(u, v, W2, b2, out);
}